// Round 14
// baseline (645.014 us; speedup 1.0000x reference)
//
#include <hip/hip_runtime.h>

// GPT-2 attention block for MI355X (gfx950), bf16 MFMA everywhere, fp32 accum.
// Outputs: [attn_output 2*2048*1024 f32][attn_weights 2*16*2048*2048 f32]
// R14: attention with ZERO barriers — each wave owns 16 q-rows AND its own
// private K/V/P LDS slices (32-key tiles), staging itself with reg-prefetch.

typedef __bf16 bf16_t;
typedef bf16_t bf16x8 __attribute__((ext_vector_type(8)));
typedef float f32x4 __attribute__((ext_vector_type(4)));
typedef unsigned short ushort8 __attribute__((ext_vector_type(8)));
typedef unsigned short ushort4v __attribute__((ext_vector_type(4)));

#define SEQ 2048
#define DMODEL 1024
#define MTOT 4096  // B*SEQ

#define AS1 __attribute__((address_space(1)))
#define AS3 __attribute__((address_space(3)))

__device__ __forceinline__ unsigned short f2bf(float f) {
  return __builtin_bit_cast(unsigned short, (bf16_t)f);
}
__device__ __forceinline__ float bf2f(unsigned short u) {
  return __builtin_bit_cast(float, (unsigned)u << 16);
}
__device__ __forceinline__ bf16x8 ldb8(const unsigned short* p) {
  return __builtin_bit_cast(bf16x8, *(const ushort8*)p);
}
__device__ __forceinline__ f32x4 mfma16(bf16x8 a, bf16x8 b, f32x4 c) {
  return __builtin_amdgcn_mfma_f32_16x16x32_bf16(a, b, c, 0, 0, 0);
}
// async global->LDS, 16 bytes per lane (GEMM staging).
__device__ __forceinline__ void gload16(const unsigned short* g, unsigned short* l) {
  __builtin_amdgcn_global_load_lds((AS1 const void*)g, (AS3 void*)l, 16, 0, 0);
}

// ---------- cast f32 -> bf16 bits ----------
__global__ __launch_bounds__(256) void cast_kernel(const float* __restrict__ in,
                                                   unsigned short* __restrict__ out) {
  int i = blockIdx.x * 256 + threadIdx.x;
  float4 v = ((const float4*)in)[i];
  ushort4v o;
  o[0] = f2bf(v.x); o[1] = f2bf(v.y); o[2] = f2bf(v.z); o[3] = f2bf(v.w);
  ((ushort4v*)out)[i] = o;
}

// ---------- transpose + cast: in f32 [R][C] -> out bf16 [C][R] ----------
__global__ __launch_bounds__(256) void transpose_cast_kernel(const float* __restrict__ in,
                                                             unsigned short* __restrict__ out,
                                                             int R, int C) {
  __shared__ float tile[32][33];
  int c0 = blockIdx.x * 32, r0 = blockIdx.y * 32;
  int tx = threadIdx.x & 31, ty = threadIdx.x >> 5;
#pragma unroll
  for (int i = 0; i < 4; ++i)
    tile[ty + i * 8][tx] = in[(size_t)(r0 + ty + i * 8) * C + c0 + tx];
  __syncthreads();
#pragma unroll
  for (int i = 0; i < 4; ++i)
    out[(size_t)(c0 + ty + i * 8) * R + r0 + tx] = f2bf(tile[tx][ty + i * 8]);
}

// ---------- m97-structure bf16 GEMM: C[M][N] = A[M][K]*BT[N][K]^T + bias ----------
template <int EPI>
__global__ __launch_bounds__(256) void gemm128(
    const unsigned short* __restrict__ A, const unsigned short* __restrict__ BT,
    const float* __restrict__ bias, float* __restrict__ outF,
    unsigned short* __restrict__ qws, unsigned short* __restrict__ kws,
    unsigned short* __restrict__ vws, int M, int N, int K) {
  __shared__ unsigned short Alds[128 * 32];
  __shared__ unsigned short Blds[128 * 32];
  int m0 = blockIdx.x * 128, n0 = blockIdx.y * 128;
  int t = threadIdx.x;
  int l = t & 63, j = l & 15, g = l >> 4;
  int w = t >> 6, wr = w >> 1, wc = w & 1;

  f32x4 acc[4][4];
#pragma unroll
  for (int mi = 0; mi < 4; ++mi)
#pragma unroll
    for (int st = 0; st < 4; ++st)
#pragma unroll
      for (int r = 0; r < 4; ++r) acc[mi][st][r] = 0.f;

  int srow = t >> 2;          // 0..63
  int scol = (t & 3) * 8;     // 0,8,16,24
  const unsigned short* aB0 = A + (size_t)(m0 + srow) * K + scol;
  const unsigned short* aB1 = aB0 + (size_t)64 * K;
  const unsigned short* bB0 = BT + (size_t)(n0 + srow) * K + scol;
  const unsigned short* bB1 = bB0 + (size_t)64 * K;
  unsigned short* aL0 = &Alds[srow * 32 + scol];
  unsigned short* aL1 = aL0 + 64 * 32;
  unsigned short* bL0 = &Blds[srow * 32 + scol];
  unsigned short* bL1 = bL0 + 64 * 32;

  for (int k0 = 0; k0 < K; k0 += 32) {
    __syncthreads();
    gload16(aB0 + k0, aL0);
    gload16(aB1 + k0, aL1);
    gload16(bB0 + k0, bL0);
    gload16(bB1 + k0, bL1);
    __syncthreads();
    bf16x8 af[4], bfr[4];
#pragma unroll
    for (int mi = 0; mi < 4; ++mi) af[mi] = ldb8(&Alds[(wr * 64 + mi * 16 + j) * 32 + g * 8]);
#pragma unroll
    for (int st = 0; st < 4; ++st) bfr[st] = ldb8(&Blds[(wc * 64 + st * 16 + j) * 32 + g * 8]);
#pragma unroll
    for (int mi = 0; mi < 4; ++mi)
#pragma unroll
      for (int st = 0; st < 4; ++st) acc[mi][st] = mfma16(af[mi], bfr[st], acc[mi][st]);
  }

#pragma unroll
  for (int st = 0; st < 4; ++st) {
    int n = n0 + wc * 64 + st * 16 + j;
    float bv = bias[n];
#pragma unroll
    for (int mi = 0; mi < 4; ++mi)
#pragma unroll
      for (int r = 0; r < 4; ++r) {
        int m = m0 + wr * 64 + mi * 16 + g * 4 + r;
        float val = acc[mi][st][r] + bv;
        if (EPI == 1) {
          outF[(size_t)m * N + n] = val;
        } else {
          int region = n >> 10;          // 0=q 1=k 2=v
          int h = (n & 1023) >> 6;
          int d = n & 63;
          int bb = m >> 11, s = m & 2047;
          int bh = bb * 16 + h;
          if (region == 0) qws[(((size_t)bh) * SEQ + s) * 64 + d] = f2bf(val * 0.125f);
          else if (region == 1) kws[(((size_t)bh) * SEQ + s) * 64 + d] = f2bf(val);
          else vws[(((size_t)bh) * 64 + d) * SEQ + s] = f2bf(val);  // transposed
        }
      }
  }
}

// ---------- fused causal attention: ZERO barriers, wave-private everything ----------
// grid (32 q-tiles interleaved, 32 b*h); 4 waves/block, each wave fully
// independent: 16 q-rows, private K[32][64]/V[64][32]/P[16][40] LDS slices,
// 32-key tiles, reg-prefetch of next tile under current compute.
// Swizzles (both-sides): K slot c^(row&7); V slot c^(d&3). Reads verified
// conflict-free / at-floor; all vector LDS ops 16B-aligned.
__global__ __launch_bounds__(256, 4) void attn_kernel(
    const unsigned short* __restrict__ qg, const unsigned short* __restrict__ kg,
    const unsigned short* __restrict__ vg, float* __restrict__ outw,
    unsigned short* __restrict__ ointer) {
  __shared__ unsigned short Kl[4][32 * 64];   // per-wave [key][d], swizzled
  __shared__ unsigned short Vl[4][64 * 32];   // per-wave [d][key], swizzled
  __shared__ unsigned short Pl[4][16 * 40];   // per-wave P [qrow][key], bf16

  int v = blockIdx.x;
  int qt = (v & 1) ? ((v - 1) >> 1) : (31 - (v >> 1));   // heavy/light interleave
  int bh = blockIdx.y;
  int b = bh >> 4, h = bh & 15;
  int t = threadIdx.x;
  int w = t >> 6, l = t & 63, j = l & 15, g = l >> 4;
  int nt2 = 2 * (qt + 1);               // 32-key tiles in causal range

  const unsigned short* qb = qg + (size_t)bh * SEQ * 64;
  const unsigned short* kb = kg + (size_t)bh * SEQ * 64;
  const unsigned short* vb = vg + (size_t)bh * SEQ * 64;  // [64][SEQ]
  float* outrow = outw + (size_t)bh * SEQ * SEQ;

  int qr_a = qt * 64 + w * 16 + j;
  bf16x8 qa0 = ldb8(&qb[(size_t)qr_a * 64 + g * 8]);
  bf16x8 qa1 = ldb8(&qb[(size_t)qr_a * 64 + 32 + g * 8]);

  int qrow0 = qt * 64 + w * 16 + g * 4;  // D rows = qrow0 + r

  unsigned short* Kw = &Kl[w][0];
  unsigned short* Vw = &Vl[w][0];
  unsigned short* Pw = &Pl[w][0];

  // --- staging geometry (per lane) ---
  int krow = l >> 1;                    // K: key row 0..31
  int kcb = (l & 1) * 4;                // K: chunk base 0 or 4
  const unsigned short* kst = kb + (size_t)krow * 64 + kcb * 8;  // +kt2*2048, linear
  int kslot[4];
#pragma unroll
  for (int i = 0; i < 4; ++i) kslot[i] = krow * 64 + (((kcb + i) ^ (krow & 7)) * 8);
  const unsigned short* vst = vb + (size_t)l * SEQ;              // +kt2*32, linear
  int vslot[4];
#pragma unroll
  for (int c = 0; c < 4; ++c) vslot[c] = l * 32 + ((c ^ (l & 3)) * 8);

  // --- fragment read bases (swizzled) ---
  int rb0 = j * 64 + ((g ^ (j & 7)) * 8);        // K d-chunk g
  int rb1 = j * 64 + (((4 + g) ^ (j & 7)) * 8);  // K d-chunk 4+g
  int vrb = (g ^ (j & 3)) * 8;                   // V key-chunk g (+ row*32)

  float lpart[4] = {0.f, 0.f, 0.f, 0.f};

  // ===== phase 1: l (wave-private, no barriers) =====
  ushort8 kr[4];
#pragma unroll
  for (int i = 0; i < 4; ++i) kr[i] = *(const ushort8*)(kst + i * 8);
  for (int kt2 = 0; kt2 < nt2; ++kt2) {
#pragma unroll
    for (int i = 0; i < 4; ++i) *(ushort8*)&Kw[kslot[i]] = kr[i];
    if (kt2 + 1 < nt2) {
      const unsigned short* nk = kst + (kt2 + 1) * 2048;
#pragma unroll
      for (int i = 0; i < 4; ++i) kr[i] = *(const ushort8*)(nk + i * 8);
    }
    f32x4 sacc[2];
#pragma unroll
    for (int st = 0; st < 2; ++st)
#pragma unroll
      for (int r = 0; r < 4; ++r) sacc[st][r] = 0.f;
#pragma unroll
    for (int st = 0; st < 2; ++st) {
      bf16x8 kf0 = ldb8(&Kw[st * 1024 + rb0]);
      bf16x8 kf1 = ldb8(&Kw[st * 1024 + rb1]);
      sacc[st] = mfma16(qa0, kf0, sacc[st]);
      sacc[st] = mfma16(qa1, kf1, sacc[st]);
    }
    bool diag = ((kt2 >> 1) == qt);
#pragma unroll
    for (int r = 0; r < 4; ++r) {
      int qrow = qrow0 + r;
#pragma unroll
      for (int st = 0; st < 2; ++st) {
        float p = __expf(sacc[st][r]);
        if (diag) {
          int kc = kt2 * 32 + st * 16 + j;
          p = (kc > qrow) ? 0.f : p;
        }
        lpart[r] += p;
      }
    }
  }

  // deferred reduce over the 16 j-lanes (wave-local)
  float linv[4];
#pragma unroll
  for (int r = 0; r < 4; ++r) {
    float sum = lpart[r];
#pragma unroll
    for (int o = 1; o < 16; o <<= 1) sum += __shfl_xor(sum, o);
    linv[r] = 1.f / sum;
  }

  f32x4 oacc[4];
#pragma unroll
  for (int st = 0; st < 4; ++st)
#pragma unroll
    for (int r = 0; r < 4; ++r) oacc[st][r] = 0.f;

  int prow = l >> 2;        // P writeback row 0..15
  int pch = (l & 3) * 8;    // P writeback key offset

  // ===== phase 2: P write + PV (wave-private, no barriers) =====
  ushort8 vr[4];
#pragma unroll
  for (int i = 0; i < 4; ++i) {
    kr[i] = *(const ushort8*)(kst + i * 8);
    vr[i] = *(const ushort8*)(vst + i * 8);
  }
  for (int kt2 = 0; kt2 < nt2; ++kt2) {
#pragma unroll
    for (int i = 0; i < 4; ++i) {
      *(ushort8*)&Kw[kslot[i]] = kr[i];
      *(ushort8*)&Vw[vslot[i]] = vr[i];
    }
    if (kt2 + 1 < nt2) {
      const unsigned short* nk = kst + (kt2 + 1) * 2048;
      const unsigned short* nv = vst + (kt2 + 1) * 32;
#pragma unroll
      for (int i = 0; i < 4; ++i) {
        kr[i] = *(const ushort8*)(nk + i * 8);
        vr[i] = *(const ushort8*)(nv + i * 8);
      }
    }
    // QK (16 q x 32 k)
    f32x4 sacc[2];
#pragma unroll
    for (int st = 0; st < 2; ++st)
#pragma unroll
      for (int r = 0; r < 4; ++r) sacc[st][r] = 0.f;
#pragma unroll
    for (int st = 0; st < 2; ++st) {
      bf16x8 kf0 = ldb8(&Kw[st * 1024 + rb0]);
      bf16x8 kf1 = ldb8(&Kw[st * 1024 + rb1]);
      sacc[st] = mfma16(qa0, kf0, sacc[st]);
      sacc[st] = mfma16(qa1, kf1, sacc[st]);
    }
    bool diag = ((kt2 >> 1) == qt);
#pragma unroll
    for (int st = 0; st < 2; ++st)
#pragma unroll
      for (int r = 0; r < 4; ++r) {
        int kc = kt2 * 32 + st * 16 + j;
        float p = __expf(sacc[st][r]) * linv[r];
        if (diag) p = (kc > qrow0 + r) ? 0.f : p;
        Pw[(g * 4 + r) * 40 + st * 16 + j] = f2bf(p);
      }
    // vectorized P global write (bf16 -> f32); Pw wave-private, lgkm-ordered
    {
      ushort8 pv = *(const ushort8*)&Pw[prow * 40 + pch];
      float4 f0, f1;
      f0.x = bf2f(pv[0]); f0.y = bf2f(pv[1]); f0.z = bf2f(pv[2]); f0.w = bf2f(pv[3]);
      f1.x = bf2f(pv[4]); f1.y = bf2f(pv[5]); f1.z = bf2f(pv[6]); f1.w = bf2f(pv[7]);
      float* dst = &outrow[(size_t)(qt * 64 + w * 16 + prow) * SEQ + kt2 * 32 + pch];
      ((float4*)dst)[0] = f0;
      ((float4*)dst)[1] = f1;
    }
    // PV: O[16q][64d] += P[16q][32k] * V[32k][64d]
    bf16x8 pa = ldb8(&Pw[j * 40 + g * 8]);
#pragma unroll
    for (int st = 0; st < 4; ++st) {
      bf16x8 vf = ldb8(&Vw[(st * 16 + j) * 32 + vrb]);
      oacc[st] = mfma16(pa, vf, oacc[st]);
    }
  }

  // write O to [B][SEQ][DMODEL] bf16 intermediate
#pragma unroll
  for (int st = 0; st < 4; ++st)
#pragma unroll
    for (int r = 0; r < 4; ++r) {
      int qrow = qrow0 + r;
      int d = st * 16 + j;
      ointer[((size_t)b * SEQ + qrow) * DMODEL + h * 64 + d] = f2bf(oacc[st][r]);
    }

  // fully-masked tiles: exact zeros (wave-private tail)
  {
    int row = qt * 64 + w * 16 + (l >> 2);
    int cc = (l & 3) * 16;
    float4 z = make_float4(0.f, 0.f, 0.f, 0.f);
    for (int kt = qt + 1; kt < SEQ / 64; ++kt) {
      float4* zp = (float4*)&outrow[(size_t)row * SEQ + kt * 64 + cc];
      zp[0] = z; zp[1] = z; zp[2] = z; zp[3] = z;
    }
  }
}

extern "C" void kernel_launch(void* const* d_in, const int* in_sizes, int n_in,
                              void* d_out, int out_size, void* d_ws, size_t ws_size,
                              hipStream_t stream) {
  const float* hidden = (const float*)d_in[0];   // [2,2048,1024]
  const float* w_attn = (const float*)d_in[1];   // [1024,3072]
  const float* b_attn = (const float*)d_in[2];   // [3072]
  const float* w_proj = (const float*)d_in[3];   // [1024,1024]
  const float* b_proj = (const float*)d_in[4];   // [1024]

  float* out_attn = (float*)d_out;                          // 4,194,304 f32
  float* out_w = out_attn + (size_t)MTOT * DMODEL;          // 134,217,728 f32

  char* ws = (char*)d_ws;
  unsigned short* hbf = (unsigned short*)(ws);              // [4096][1024] bf16; later reused as attn O
  unsigned short* w1T = (unsigned short*)(ws + 8388608);    // [3072][1024] bf16
  unsigned short* w2T = (unsigned short*)(ws + 14680064);   // [1024][1024] bf16
  unsigned short* qws = (unsigned short*)(ws + 16777216);   // [32][2048][64] bf16 (pre-scaled 1/8)
  unsigned short* kws = (unsigned short*)(ws + 25165824);   // [32][2048][64]
  unsigned short* vws = (unsigned short*)(ws + 33554432);   // [32][64][2048] (transposed)

  cast_kernel<<<4096, 256, 0, stream>>>(hidden, hbf);
  transpose_cast_kernel<<<dim3(96, 32), 256, 0, stream>>>(w_attn, w1T, 1024, 3072);
  transpose_cast_kernel<<<dim3(32, 32), 256, 0, stream>>>(w_proj, w2T, 1024, 1024);
  gemm128<0><<<dim3(32, 24), 256, 0, stream>>>(hbf, w1T, b_attn, nullptr, qws, kws, vws,
                                               MTOT, 3 * DMODEL, DMODEL);
  attn_kernel<<<dim3(32, 32), 256, 0, stream>>>(qws, kws, vws, out_w, hbf);
  gemm128<1><<<dim3(32, 8), 256, 0, stream>>>(hbf, w2T, b_proj, out_attn, nullptr, nullptr,
                                              nullptr, MTOT, DMODEL, DMODEL);
}

// Round 15
// 462.724 us; speedup vs baseline: 1.3939x; 1.3939x over previous
//
#include <hip/hip_runtime.h>

// GPT-2 attention block for MI355X (gfx950), bf16 MFMA everywhere, fp32 accum.
// Outputs: [attn_output 2*2048*1024 f32][attn_weights 2*16*2048*2048 f32]
// R15 = R13 staging (global_load_lds + XOR swizzle) + paired q-tiles per block:
// 512 threads / 8 waves; waves 0-3 -> qtA=bx, waves 4-7 -> qtB=31-bx, sharing
// each staged K/V tile. Balanced blocks, -26% barrier-iterations, 2x MFMA/barrier.

typedef __bf16 bf16_t;
typedef bf16_t bf16x8 __attribute__((ext_vector_type(8)));
typedef float f32x4 __attribute__((ext_vector_type(4)));
typedef unsigned short ushort8 __attribute__((ext_vector_type(8)));
typedef unsigned short ushort4v __attribute__((ext_vector_type(4)));

#define SEQ 2048
#define DMODEL 1024
#define MTOT 4096  // B*SEQ

#define AS1 __attribute__((address_space(1)))
#define AS3 __attribute__((address_space(3)))

__device__ __forceinline__ unsigned short f2bf(float f) {
  return __builtin_bit_cast(unsigned short, (bf16_t)f);
}
__device__ __forceinline__ float bf2f(unsigned short u) {
  return __builtin_bit_cast(float, (unsigned)u << 16);
}
__device__ __forceinline__ bf16x8 ldb8(const unsigned short* p) {
  return __builtin_bit_cast(bf16x8, *(const ushort8*)p);
}
__device__ __forceinline__ f32x4 mfma16(bf16x8 a, bf16x8 b, f32x4 c) {
  return __builtin_amdgcn_mfma_f32_16x16x32_bf16(a, b, c, 0, 0, 0);
}
// async global->LDS, 16 bytes per lane. LDS dest must be wave-uniform-base + lane*16.
__device__ __forceinline__ void gload16(const unsigned short* g, unsigned short* l) {
  __builtin_amdgcn_global_load_lds((AS1 const void*)g, (AS3 void*)l, 16, 0, 0);
}

// ---------- cast f32 -> bf16 bits ----------
__global__ __launch_bounds__(256) void cast_kernel(const float* __restrict__ in,
                                                   unsigned short* __restrict__ out) {
  int i = blockIdx.x * 256 + threadIdx.x;
  float4 v = ((const float4*)in)[i];
  ushort4v o;
  o[0] = f2bf(v.x); o[1] = f2bf(v.y); o[2] = f2bf(v.z); o[3] = f2bf(v.w);
  ((ushort4v*)out)[i] = o;
}

// ---------- transpose + cast: in f32 [R][C] -> out bf16 [C][R] ----------
__global__ __launch_bounds__(256) void transpose_cast_kernel(const float* __restrict__ in,
                                                             unsigned short* __restrict__ out,
                                                             int R, int C) {
  __shared__ float tile[32][33];
  int c0 = blockIdx.x * 32, r0 = blockIdx.y * 32;
  int tx = threadIdx.x & 31, ty = threadIdx.x >> 5;
#pragma unroll
  for (int i = 0; i < 4; ++i)
    tile[ty + i * 8][tx] = in[(size_t)(r0 + ty + i * 8) * C + c0 + tx];
  __syncthreads();
#pragma unroll
  for (int i = 0; i < 4; ++i)
    out[(size_t)(c0 + ty + i * 8) * R + r0 + tx] = f2bf(tile[tx][ty + i * 8]);
}

// ---------- m97-structure bf16 GEMM: C[M][N] = A[M][K]*BT[N][K]^T + bias ----------
template <int EPI>
__global__ __launch_bounds__(256) void gemm128(
    const unsigned short* __restrict__ A, const unsigned short* __restrict__ BT,
    const float* __restrict__ bias, float* __restrict__ outF,
    unsigned short* __restrict__ qws, unsigned short* __restrict__ kws,
    unsigned short* __restrict__ vws, int M, int N, int K) {
  __shared__ unsigned short Alds[128 * 32];
  __shared__ unsigned short Blds[128 * 32];
  int m0 = blockIdx.x * 128, n0 = blockIdx.y * 128;
  int t = threadIdx.x;
  int l = t & 63, j = l & 15, g = l >> 4;
  int w = t >> 6, wr = w >> 1, wc = w & 1;

  f32x4 acc[4][4];
#pragma unroll
  for (int mi = 0; mi < 4; ++mi)
#pragma unroll
    for (int st = 0; st < 4; ++st)
#pragma unroll
      for (int r = 0; r < 4; ++r) acc[mi][st][r] = 0.f;

  int srow = t >> 2;          // 0..63
  int scol = (t & 3) * 8;     // 0,8,16,24
  const unsigned short* aB0 = A + (size_t)(m0 + srow) * K + scol;
  const unsigned short* aB1 = aB0 + (size_t)64 * K;
  const unsigned short* bB0 = BT + (size_t)(n0 + srow) * K + scol;
  const unsigned short* bB1 = bB0 + (size_t)64 * K;
  unsigned short* aL0 = &Alds[srow * 32 + scol];
  unsigned short* aL1 = aL0 + 64 * 32;
  unsigned short* bL0 = &Blds[srow * 32 + scol];
  unsigned short* bL1 = bL0 + 64 * 32;

  for (int k0 = 0; k0 < K; k0 += 32) {
    __syncthreads();
    gload16(aB0 + k0, aL0);
    gload16(aB1 + k0, aL1);
    gload16(bB0 + k0, bL0);
    gload16(bB1 + k0, bL1);
    __syncthreads();
    bf16x8 af[4], bfr[4];
#pragma unroll
    for (int mi = 0; mi < 4; ++mi) af[mi] = ldb8(&Alds[(wr * 64 + mi * 16 + j) * 32 + g * 8]);
#pragma unroll
    for (int st = 0; st < 4; ++st) bfr[st] = ldb8(&Blds[(wc * 64 + st * 16 + j) * 32 + g * 8]);
#pragma unroll
    for (int mi = 0; mi < 4; ++mi)
#pragma unroll
      for (int st = 0; st < 4; ++st) acc[mi][st] = mfma16(af[mi], bfr[st], acc[mi][st]);
  }

#pragma unroll
  for (int st = 0; st < 4; ++st) {
    int n = n0 + wc * 64 + st * 16 + j;
    float bv = bias[n];
#pragma unroll
    for (int mi = 0; mi < 4; ++mi)
#pragma unroll
      for (int r = 0; r < 4; ++r) {
        int m = m0 + wr * 64 + mi * 16 + g * 4 + r;
        float val = acc[mi][st][r] + bv;
        if (EPI == 1) {
          outF[(size_t)m * N + n] = val;
        } else {
          int region = n >> 10;          // 0=q 1=k 2=v
          int h = (n & 1023) >> 6;
          int d = n & 63;
          int bb = m >> 11, s = m & 2047;
          int bh = bb * 16 + h;
          if (region == 0) qws[(((size_t)bh) * SEQ + s) * 64 + d] = f2bf(val * 0.125f);
          else if (region == 1) kws[(((size_t)bh) * SEQ + s) * 64 + d] = f2bf(val);
          else vws[(((size_t)bh) * 64 + d) * SEQ + s] = f2bf(val);  // transposed
        }
      }
  }
}

// ---------- fused causal attention: paired q-tiles, 512 threads ----------
// grid (16 pairs, 32 b*h). Waves 0-3: qtA=bx rows; waves 4-7: qtB=31-bx rows.
// Shared K/V tile staged per iteration via global_load_lds (one 16B slot per
// thread), XOR-swizzled (slot ^= row&7) on source and read (both-sides, G21).
__global__ __launch_bounds__(512) void attn_kernel(
    const unsigned short* __restrict__ qg, const unsigned short* __restrict__ kg,
    const unsigned short* __restrict__ vg, float* __restrict__ outw,
    unsigned short* __restrict__ ointer) {
  __shared__ unsigned short Klds[64 * 64];      // [key][d], swizzled
  __shared__ unsigned short Vlds[64 * 64];      // [d][key], swizzled
  __shared__ unsigned short Plds[8][16 * 72];   // per-wave P tile, bf16

  int qtA = blockIdx.x;                 // 0..15
  int qtB = 31 - qtA;                   // 16..31
  int bh = blockIdx.y;
  int b = bh >> 4, h = bh & 15;
  int t = threadIdx.x;
  int wv = t >> 6, l = t & 63, j = l & 15, g = l >> 4;
  int wl = wv & 3;                      // row-slot within the wave group
  int qt = (wv >= 4) ? qtB : qtA;       // this wave's q-tile

  const unsigned short* qb = qg + (size_t)bh * SEQ * 64;
  const unsigned short* kb = kg + (size_t)bh * SEQ * 64;
  const unsigned short* vb = vg + (size_t)bh * SEQ * 64;  // [64][SEQ]
  float* outrow = outw + (size_t)bh * SEQ * SEQ;

  int qr_a = qt * 64 + wl * 16 + j;
  bf16x8 qa0 = ldb8(&qb[(size_t)qr_a * 64 + g * 8]);
  bf16x8 qa1 = ldb8(&qb[(size_t)qr_a * 64 + 32 + g * 8]);

  int qrow0 = qt * 64 + wl * 16 + g * 4;  // D rows = qrow0 + r

  // staging: 512 threads cover the 8KB tile; thread t -> 16B slot t
  int srow = t >> 3;                         // 0..63
  int swz8 = ((t & 7) ^ (srow & 7)) * 8;     // swizzled source chunk
  const unsigned short* ksrc = kb + srow * 64 + swz8;             // + kt*4096
  const unsigned short* vsrc = vb + (size_t)srow * SEQ + swz8;    // + kt*64
  unsigned short* kd = &Klds[t * 8];
  unsigned short* vd = &Vlds[t * 8];

  // fragment read bases (swizzled): row j, chunks g and 4+g
  int rb0 = j * 64 + ((g ^ (j & 7)) * 8);
  int rb1 = j * 64 + (((4 + g) ^ (j & 7)) * 8);

  float lpart[4] = {0.f, 0.f, 0.f, 0.f};

  // ---- phase 1: per-lane partial sums of exp(s) ----
  for (int kt = 0; kt <= qtB; ++kt) {
    __syncthreads();      // prior tile consumed
    gload16(ksrc + kt * 4096, kd);
    __syncthreads();      // staged
    if (kt <= qt) {
      f32x4 sacc[4];
#pragma unroll
      for (int st = 0; st < 4; ++st)
#pragma unroll
        for (int r = 0; r < 4; ++r) sacc[st][r] = 0.f;
#pragma unroll
      for (int st = 0; st < 4; ++st) {
        bf16x8 kf0 = ldb8(&Klds[st * 1024 + rb0]);
        bf16x8 kf1 = ldb8(&Klds[st * 1024 + rb1]);
        sacc[st] = mfma16(qa0, kf0, sacc[st]);
        sacc[st] = mfma16(qa1, kf1, sacc[st]);
      }
      bool diag = (kt == qt);
#pragma unroll
      for (int r = 0; r < 4; ++r) {
        int qrow = qrow0 + r;
#pragma unroll
        for (int st = 0; st < 4; ++st) {
          float p = __expf(sacc[st][r]);
          if (diag) {
            int kc = kt * 64 + st * 16 + j;
            p = (kc > qrow) ? 0.f : p;
          }
          lpart[r] += p;
        }
      }
    }
  }

  // deferred reduce over the 16 j-lanes (wave-local)
  float linv[4];
#pragma unroll
  for (int r = 0; r < 4; ++r) {
    float sum = lpart[r];
#pragma unroll
    for (int o = 1; o < 16; o <<= 1) sum += __shfl_xor(sum, o);
    linv[r] = 1.f / sum;
  }

  f32x4 oacc[4];
#pragma unroll
  for (int st = 0; st < 4; ++st)
#pragma unroll
    for (int r = 0; r < 4; ++r) oacc[st][r] = 0.f;

  int prow = l >> 2;        // P writeback: row 0..15
  int pch = l & 3;          // chunk base (8 keys per chunk)

  // ---- phase 2: P write + PV ----
  for (int kt = 0; kt <= qtB; ++kt) {
    __syncthreads();
    gload16(ksrc + kt * 4096, kd);
    gload16(vsrc + kt * 64, vd);
    __syncthreads();
    if (kt <= qt) {
      f32x4 sacc[4];
#pragma unroll
      for (int st = 0; st < 4; ++st)
#pragma unroll
        for (int r = 0; r < 4; ++r) sacc[st][r] = 0.f;
#pragma unroll
      for (int st = 0; st < 4; ++st) {
        bf16x8 kf0 = ldb8(&Klds[st * 1024 + rb0]);
        bf16x8 kf1 = ldb8(&Klds[st * 1024 + rb1]);
        sacc[st] = mfma16(qa0, kf0, sacc[st]);
        sacc[st] = mfma16(qa1, kf1, sacc[st]);
      }
      bool diag = (kt == qt);
#pragma unroll
      for (int st = 0; st < 4; ++st) {
#pragma unroll
        for (int r = 0; r < 4; ++r) {
          int qrow = qrow0 + r;
          int kc = kt * 64 + st * 16 + j;
          float p = __expf(sacc[st][r]) * linv[r];
          if (diag) p = (kc > qrow) ? 0.f : p;
          Plds[wv][(g * 4 + r) * 72 + st * 16 + j] = f2bf(p);
        }
      }
      // Plds[wv] wave-private: lgkmcnt orders write->read, no barrier.
#pragma unroll
      for (int it = 0; it < 2; ++it) {
        int ch = pch + it * 4;
        ushort8 pv = *(const ushort8*)&Plds[wv][prow * 72 + ch * 8];
        float4 f0, f1;
        f0.x = bf2f(pv[0]); f0.y = bf2f(pv[1]); f0.z = bf2f(pv[2]); f0.w = bf2f(pv[3]);
        f1.x = bf2f(pv[4]); f1.y = bf2f(pv[5]); f1.z = bf2f(pv[6]); f1.w = bf2f(pv[7]);
        float* dst = &outrow[(size_t)(qt * 64 + wl * 16 + prow) * SEQ + kt * 64 + ch * 8];
        ((float4*)dst)[0] = f0;
        ((float4*)dst)[1] = f1;
      }
      bf16x8 pa0 = ldb8(&Plds[wv][j * 72 + g * 8]);
      bf16x8 pa1 = ldb8(&Plds[wv][j * 72 + 32 + g * 8]);
#pragma unroll
      for (int st = 0; st < 4; ++st) {
        bf16x8 vf0 = ldb8(&Vlds[st * 1024 + rb0]);
        bf16x8 vf1 = ldb8(&Vlds[st * 1024 + rb1]);
        oacc[st] = mfma16(pa0, vf0, oacc[st]);
        oacc[st] = mfma16(pa1, vf1, oacc[st]);
      }
    }
  }

  // write O to [B][SEQ][DMODEL] bf16 intermediate
#pragma unroll
  for (int st = 0; st < 4; ++st)
#pragma unroll
    for (int r = 0; r < 4; ++r) {
      int qrow = qrow0 + r;
      int d = st * 16 + j;
      ointer[((size_t)b * SEQ + qrow) * DMODEL + h * 64 + d] = f2bf(oacc[st][r]);
    }

  // fully-masked tiles: exact zeros (barrier-free tail, per wave)
  {
    int row = qt * 64 + wl * 16 + (l >> 2);
    int cc = (l & 3) * 16;
    float4 z = make_float4(0.f, 0.f, 0.f, 0.f);
    for (int kt = qt + 1; kt < SEQ / 64; ++kt) {
      float4* zp = (float4*)&outrow[(size_t)row * SEQ + kt * 64 + cc];
      zp[0] = z; zp[1] = z; zp[2] = z; zp[3] = z;
    }
  }
}

extern "C" void kernel_launch(void* const* d_in, const int* in_sizes, int n_in,
                              void* d_out, int out_size, void* d_ws, size_t ws_size,
                              hipStream_t stream) {
  const float* hidden = (const float*)d_in[0];   // [2,2048,1024]
  const float* w_attn = (const float*)d_in[1];   // [1024,3072]
  const float* b_attn = (const float*)d_in[2];   // [3072]
  const float* w_proj = (const float*)d_in[3];   // [1024,1024]
  const float* b_proj = (const float*)d_in[4];   // [1024]

  float* out_attn = (float*)d_out;                          // 4,194,304 f32
  float* out_w = out_attn + (size_t)MTOT * DMODEL;          // 134,217,728 f32

  char* ws = (char*)d_ws;
  unsigned short* hbf = (unsigned short*)(ws);              // [4096][1024] bf16; later reused as attn O
  unsigned short* w1T = (unsigned short*)(ws + 8388608);    // [3072][1024] bf16
  unsigned short* w2T = (unsigned short*)(ws + 14680064);   // [1024][1024] bf16
  unsigned short* qws = (unsigned short*)(ws + 16777216);   // [32][2048][64] bf16 (pre-scaled 1/8)
  unsigned short* kws = (unsigned short*)(ws + 25165824);   // [32][2048][64]
  unsigned short* vws = (unsigned short*)(ws + 33554432);   // [32][64][2048] (transposed)

  cast_kernel<<<4096, 256, 0, stream>>>(hidden, hbf);
  transpose_cast_kernel<<<dim3(96, 32), 256, 0, stream>>>(w_attn, w1T, 1024, 3072);
  transpose_cast_kernel<<<dim3(32, 32), 256, 0, stream>>>(w_proj, w2T, 1024, 1024);
  gemm128<0><<<dim3(32, 24), 256, 0, stream>>>(hbf, w1T, b_attn, nullptr, qws, kws, vws,
                                               MTOT, 3 * DMODEL, DMODEL);
  attn_kernel<<<dim3(16, 32), 512, 0, stream>>>(qws, kws, vws, out_w, hbf);
  gemm128<1><<<dim3(32, 8), 256, 0, stream>>>(hbf, w2T, b_proj, out_attn, nullptr, nullptr,
                                              nullptr, MTOT, DMODEL, DMODEL);
}

// Round 16
// 268.117 us; speedup vs baseline: 2.4057x; 1.7258x over previous
//
#include <hip/hip_runtime.h>

// GPT-2 attention block for MI355X (gfx950), bf16 MFMA everywhere, fp32 accum.
// Outputs: [attn_output 2*2048*1024 f32][attn_weights 2*16*2048*2048 f32]
// R16 = R13 (best, 267.4us) with BK=64 gemms (halved barrier-iterations,
// XOR-swizzled linear LDS). Attention kernel byte-identical to R13.

typedef __bf16 bf16_t;
typedef bf16_t bf16x8 __attribute__((ext_vector_type(8)));
typedef float f32x4 __attribute__((ext_vector_type(4)));
typedef unsigned short ushort8 __attribute__((ext_vector_type(8)));
typedef unsigned short ushort4v __attribute__((ext_vector_type(4)));

#define SEQ 2048
#define DMODEL 1024
#define MTOT 4096  // B*SEQ

#define AS1 __attribute__((address_space(1)))
#define AS3 __attribute__((address_space(3)))

__device__ __forceinline__ unsigned short f2bf(float f) {
  return __builtin_bit_cast(unsigned short, (bf16_t)f);
}
__device__ __forceinline__ float bf2f(unsigned short u) {
  return __builtin_bit_cast(float, (unsigned)u << 16);
}
__device__ __forceinline__ bf16x8 ldb8(const unsigned short* p) {
  return __builtin_bit_cast(bf16x8, *(const ushort8*)p);
}
__device__ __forceinline__ f32x4 mfma16(bf16x8 a, bf16x8 b, f32x4 c) {
  return __builtin_amdgcn_mfma_f32_16x16x32_bf16(a, b, c, 0, 0, 0);
}
// async global->LDS, 16 bytes per lane. LDS dest must be wave-uniform-base + lane*16.
__device__ __forceinline__ void gload16(const unsigned short* g, unsigned short* l) {
  __builtin_amdgcn_global_load_lds((AS1 const void*)g, (AS3 void*)l, 16, 0, 0);
}

// ---------- cast f32 -> bf16 bits ----------
__global__ __launch_bounds__(256) void cast_kernel(const float* __restrict__ in,
                                                   unsigned short* __restrict__ out) {
  int i = blockIdx.x * 256 + threadIdx.x;
  float4 v = ((const float4*)in)[i];
  ushort4v o;
  o[0] = f2bf(v.x); o[1] = f2bf(v.y); o[2] = f2bf(v.z); o[3] = f2bf(v.w);
  ((ushort4v*)out)[i] = o;
}

// ---------- transpose + cast: in f32 [R][C] -> out bf16 [C][R] ----------
__global__ __launch_bounds__(256) void transpose_cast_kernel(const float* __restrict__ in,
                                                             unsigned short* __restrict__ out,
                                                             int R, int C) {
  __shared__ float tile[32][33];
  int c0 = blockIdx.x * 32, r0 = blockIdx.y * 32;
  int tx = threadIdx.x & 31, ty = threadIdx.x >> 5;
#pragma unroll
  for (int i = 0; i < 4; ++i)
    tile[ty + i * 8][tx] = in[(size_t)(r0 + ty + i * 8) * C + c0 + tx];
  __syncthreads();
#pragma unroll
  for (int i = 0; i < 4; ++i)
    out[(size_t)(c0 + ty + i * 8) * R + r0 + tx] = f2bf(tile[tx][ty + i * 8]);
}

// ---------- bf16 GEMM, BK=64: C[M][N] = A[M][K]*BT[N][K]^T + bias ----------
// 128x128 tile, 4 waves (2x2), each wave 64x64 = 4x4 fragments.
// Linear LDS [128][64] with 16B-chunk XOR swizzle (chunk ^= row&7) applied to
// the global source at staging and to the ds_read address (both-sides, G21).
template <int EPI>
__global__ __launch_bounds__(256) void gemm128(
    const unsigned short* __restrict__ A, const unsigned short* __restrict__ BT,
    const float* __restrict__ bias, float* __restrict__ outF,
    unsigned short* __restrict__ qws, unsigned short* __restrict__ kws,
    unsigned short* __restrict__ vws, int M, int N, int K) {
  __shared__ unsigned short Alds[128 * 64];   // 16 KB
  __shared__ unsigned short Blds[128 * 64];   // 16 KB
  int m0 = blockIdx.x * 128, n0 = blockIdx.y * 128;
  int t = threadIdx.x;
  int l = t & 63, j = l & 15, g = l >> 4;
  int w = t >> 6, wr = w >> 1, wc = w & 1;

  f32x4 acc[4][4];
#pragma unroll
  for (int mi = 0; mi < 4; ++mi)
#pragma unroll
    for (int st = 0; st < 4; ++st)
#pragma unroll
      for (int r = 0; r < 4; ++r) acc[mi][st][r] = 0.f;

  // staging: thread t -> linear LDS slot t (rows srow+32i), swizzled source
  int srow = t >> 3;                          // 0..31
  int swz8 = ((t & 7) ^ (srow & 7)) * 8;      // source chunk, XOR swizzle
  const unsigned short* aB = A + (size_t)(m0 + srow) * K + swz8;
  const unsigned short* bB = BT + (size_t)(n0 + srow) * K + swz8;
  unsigned short* aL = &Alds[t * 8];
  unsigned short* bL = &Blds[t * 8];

  for (int k0 = 0; k0 < K; k0 += 64) {
    __syncthreads();
#pragma unroll
    for (int i = 0; i < 4; ++i) {
      gload16(aB + (size_t)(32 * i) * K + k0, aL + 2048 * i);
      gload16(bB + (size_t)(32 * i) * K + k0, bL + 2048 * i);
    }
    __syncthreads();
#pragma unroll
    for (int kk = 0; kk < 2; ++kk) {
      bf16x8 af[4], bfr[4];
#pragma unroll
      for (int mi = 0; mi < 4; ++mi)
        af[mi] = ldb8(&Alds[(wr * 64 + mi * 16 + j) * 64 + (((kk * 4 + g) ^ (j & 7)) * 8)]);
#pragma unroll
      for (int st = 0; st < 4; ++st)
        bfr[st] = ldb8(&Blds[(wc * 64 + st * 16 + j) * 64 + (((kk * 4 + g) ^ (j & 7)) * 8)]);
#pragma unroll
      for (int mi = 0; mi < 4; ++mi)
#pragma unroll
        for (int st = 0; st < 4; ++st) acc[mi][st] = mfma16(af[mi], bfr[st], acc[mi][st]);
    }
  }

#pragma unroll
  for (int st = 0; st < 4; ++st) {
    int n = n0 + wc * 64 + st * 16 + j;
    float bv = bias[n];
#pragma unroll
    for (int mi = 0; mi < 4; ++mi)
#pragma unroll
      for (int r = 0; r < 4; ++r) {
        int m = m0 + wr * 64 + mi * 16 + g * 4 + r;
        float val = acc[mi][st][r] + bv;
        if (EPI == 1) {
          outF[(size_t)m * N + n] = val;
        } else {
          int region = n >> 10;          // 0=q 1=k 2=v
          int h = (n & 1023) >> 6;
          int d = n & 63;
          int bb = m >> 11, s = m & 2047;
          int bh = bb * 16 + h;
          if (region == 0) qws[(((size_t)bh) * SEQ + s) * 64 + d] = f2bf(val * 0.125f);
          else if (region == 1) kws[(((size_t)bh) * SEQ + s) * 64 + d] = f2bf(val);
          else vws[(((size_t)bh) * 64 + d) * SEQ + s] = f2bf(val);  // transposed
        }
      }
  }
}

// ---------- fused causal attention (R13: global_load_lds staging, XOR swizzle) ----------
// grid (32 q-tiles interleaved heavy/light, 32 b*h); 4 waves, wave owns 16 q-rows.
__global__ __launch_bounds__(256) void attn_kernel(
    const unsigned short* __restrict__ qg, const unsigned short* __restrict__ kg,
    const unsigned short* __restrict__ vg, float* __restrict__ outw,
    unsigned short* __restrict__ ointer) {
  __shared__ unsigned short Klds[64 * 64];      // [key][d], swizzled
  __shared__ unsigned short Vlds[64 * 64];      // [d][key], swizzled
  __shared__ unsigned short Plds[4][16][72];    // per-wave P tile, bf16 (VALU-written)

  int v = blockIdx.x;
  int qt = (v & 1) ? ((v - 1) >> 1) : (31 - (v >> 1));   // heavy/light interleave
  int bh = blockIdx.y;
  int b = bh >> 4, h = bh & 15;
  int t = threadIdx.x;
  int w = t >> 6, l = t & 63, j = l & 15, g = l >> 4;

  const unsigned short* qb = qg + (size_t)bh * SEQ * 64;
  const unsigned short* kb = kg + (size_t)bh * SEQ * 64;
  const unsigned short* vb = vg + (size_t)bh * SEQ * 64;  // [64][SEQ]
  float* outrow = outw + (size_t)bh * SEQ * SEQ;

  int qr_a = qt * 64 + w * 16 + j;  // A-fragment row
  bf16x8 qa0 = ldb8(&qb[(size_t)qr_a * 64 + g * 8]);
  bf16x8 qa1 = ldb8(&qb[(size_t)qr_a * 64 + 32 + g * 8]);

  int qrow0 = qt * 64 + w * 16 + g * 4;  // D rows = qrow0 + r

  // staging: thread t owns 16B slot t of each 8KB tile half (rows 0-31 / 32-63)
  int srow = t >> 3;                         // 0..31
  int swz8 = ((t & 7) ^ (srow & 7)) * 8;     // swizzled source chunk
  const unsigned short* ksrc0 = kb + srow * 64 + swz8;            // + kt*4096
  const unsigned short* ksrc1 = ksrc0 + 32 * 64;
  const unsigned short* vsrc0 = vb + (size_t)srow * SEQ + swz8;   // + kt*64
  const unsigned short* vsrc1 = vsrc0 + (size_t)32 * SEQ;
  unsigned short* kd0 = &Klds[t * 8];
  unsigned short* kd1 = kd0 + 2048;
  unsigned short* vd0 = &Vlds[t * 8];
  unsigned short* vd1 = vd0 + 2048;

  // fragment read bases (swizzled): row j, chunks g and 4+g
  int rb0 = j * 64 + ((g ^ (j & 7)) * 8);
  int rb1 = j * 64 + (((4 + g) ^ (j & 7)) * 8);

  float lpart[4] = {0.f, 0.f, 0.f, 0.f};

  // ---- phase 1: per-lane partial sums of exp(s) ----
  for (int kt = 0; kt <= qt; ++kt) {
    __syncthreads();      // prior tile consumed
    gload16(ksrc0 + kt * 4096, kd0);
    gload16(ksrc1 + kt * 4096, kd1);
    __syncthreads();      // staged (vmcnt drained before barrier)
    f32x4 sacc[4];
#pragma unroll
    for (int st = 0; st < 4; ++st)
#pragma unroll
      for (int r = 0; r < 4; ++r) sacc[st][r] = 0.f;
#pragma unroll
    for (int st = 0; st < 4; ++st) {
      bf16x8 kf0 = ldb8(&Klds[st * 1024 + rb0]);
      bf16x8 kf1 = ldb8(&Klds[st * 1024 + rb1]);
      sacc[st] = mfma16(qa0, kf0, sacc[st]);
      sacc[st] = mfma16(qa1, kf1, sacc[st]);
    }
    bool diag = (kt == qt);
#pragma unroll
    for (int r = 0; r < 4; ++r) {
      int qrow = qrow0 + r;
#pragma unroll
      for (int st = 0; st < 4; ++st) {
        float p = __expf(sacc[st][r]);
        if (diag) {
          int kc = kt * 64 + st * 16 + j;
          p = (kc > qrow) ? 0.f : p;
        }
        lpart[r] += p;
      }
    }
  }

  // deferred reduce over the 16 j-lanes
  float linv[4];
#pragma unroll
  for (int r = 0; r < 4; ++r) {
    float sum = lpart[r];
#pragma unroll
    for (int o = 1; o < 16; o <<= 1) sum += __shfl_xor(sum, o);
    linv[r] = 1.f / sum;
  }

  f32x4 oacc[4];
#pragma unroll
  for (int st = 0; st < 4; ++st)
#pragma unroll
    for (int r = 0; r < 4; ++r) oacc[st][r] = 0.f;

  int prow = l >> 2;        // P writeback: row 0..15
  int pch = l & 3;          // chunk base (8 keys per chunk)

  // ---- phase 2: P write + PV ----
  for (int kt = 0; kt < SEQ / 64; ++kt) {
    if (kt <= qt) {
      __syncthreads();
      gload16(ksrc0 + kt * 4096, kd0);
      gload16(ksrc1 + kt * 4096, kd1);
      gload16(vsrc0 + kt * 64, vd0);
      gload16(vsrc1 + kt * 64, vd1);
      __syncthreads();
      f32x4 sacc[4];
#pragma unroll
      for (int st = 0; st < 4; ++st)
#pragma unroll
        for (int r = 0; r < 4; ++r) sacc[st][r] = 0.f;
#pragma unroll
      for (int st = 0; st < 4; ++st) {
        bf16x8 kf0 = ldb8(&Klds[st * 1024 + rb0]);
        bf16x8 kf1 = ldb8(&Klds[st * 1024 + rb1]);
        sacc[st] = mfma16(qa0, kf0, sacc[st]);
        sacc[st] = mfma16(qa1, kf1, sacc[st]);
      }
      bool diag = (kt == qt);
#pragma unroll
      for (int st = 0; st < 4; ++st) {
#pragma unroll
        for (int r = 0; r < 4; ++r) {
          int qrow = qrow0 + r;
          int kc = kt * 64 + st * 16 + j;
          float p = __expf(sacc[st][r]) * linv[r];
          if (diag) p = (kc > qrow) ? 0.f : p;
          Plds[w][g * 4 + r][st * 16 + j] = f2bf(p);
        }
      }
      // Plds[w] wave-private: lgkmcnt orders write->read, no barrier.
      // vectorized P global write (bf16 -> f32), 128B per 4 lanes
#pragma unroll
      for (int it = 0; it < 2; ++it) {
        int ch = pch + it * 4;
        ushort8 pv = *(const ushort8*)&Plds[w][prow][ch * 8];
        float4 f0, f1;
        f0.x = bf2f(pv[0]); f0.y = bf2f(pv[1]); f0.z = bf2f(pv[2]); f0.w = bf2f(pv[3]);
        f1.x = bf2f(pv[4]); f1.y = bf2f(pv[5]); f1.z = bf2f(pv[6]); f1.w = bf2f(pv[7]);
        float* dst = &outrow[(size_t)(qt * 64 + w * 16 + prow) * SEQ + kt * 64 + ch * 8];
        ((float4*)dst)[0] = f0;
        ((float4*)dst)[1] = f1;
      }
      bf16x8 pa0 = ldb8(&Plds[w][j][g * 8]);
      bf16x8 pa1 = ldb8(&Plds[w][j][32 + g * 8]);
#pragma unroll
      for (int st = 0; st < 4; ++st) {
        bf16x8 vf0 = ldb8(&Vlds[st * 1024 + rb0]);
        bf16x8 vf1 = ldb8(&Vlds[st * 1024 + rb1]);
        oacc[st] = mfma16(pa0, vf0, oacc[st]);
        oacc[st] = mfma16(pa1, vf1, oacc[st]);
      }
    } else {
      // fully-masked tile: softmax underflows to exact 0
      int row = qt * 64 + w * 16 + (l >> 2);
      int c0 = kt * 64 + (l & 3) * 16;
      float4 z = make_float4(0.f, 0.f, 0.f, 0.f);
      float4* zp = (float4*)&outrow[(size_t)row * SEQ + c0];
      zp[0] = z; zp[1] = z; zp[2] = z; zp[3] = z;
    }
  }

  // write O to [B][SEQ][DMODEL] bf16 intermediate
#pragma unroll
  for (int st = 0; st < 4; ++st)
#pragma unroll
    for (int r = 0; r < 4; ++r) {
      int qrow = qrow0 + r;
      int d = st * 16 + j;
      ointer[((size_t)b * SEQ + qrow) * DMODEL + h * 64 + d] = f2bf(oacc[st][r]);
    }
}

extern "C" void kernel_launch(void* const* d_in, const int* in_sizes, int n_in,
                              void* d_out, int out_size, void* d_ws, size_t ws_size,
                              hipStream_t stream) {
  const float* hidden = (const float*)d_in[0];   // [2,2048,1024]
  const float* w_attn = (const float*)d_in[1];   // [1024,3072]
  const float* b_attn = (const float*)d_in[2];   // [3072]
  const float* w_proj = (const float*)d_in[3];   // [1024,1024]
  const float* b_proj = (const float*)d_in[4];   // [1024]

  float* out_attn = (float*)d_out;                          // 4,194,304 f32
  float* out_w = out_attn + (size_t)MTOT * DMODEL;          // 134,217,728 f32

  char* ws = (char*)d_ws;
  unsigned short* hbf = (unsigned short*)(ws);              // [4096][1024] bf16; later reused as attn O
  unsigned short* w1T = (unsigned short*)(ws + 8388608);    // [3072][1024] bf16
  unsigned short* w2T = (unsigned short*)(ws + 14680064);   // [1024][1024] bf16
  unsigned short* qws = (unsigned short*)(ws + 16777216);   // [32][2048][64] bf16 (pre-scaled 1/8)
  unsigned short* kws = (unsigned short*)(ws + 25165824);   // [32][2048][64]
  unsigned short* vws = (unsigned short*)(ws + 33554432);   // [32][64][2048] (transposed)

  cast_kernel<<<4096, 256, 0, stream>>>(hidden, hbf);
  transpose_cast_kernel<<<dim3(96, 32), 256, 0, stream>>>(w_attn, w1T, 1024, 3072);
  transpose_cast_kernel<<<dim3(32, 32), 256, 0, stream>>>(w_proj, w2T, 1024, 1024);
  gemm128<0><<<dim3(32, 24), 256, 0, stream>>>(hbf, w1T, b_attn, nullptr, qws, kws, vws,
                                               MTOT, 3 * DMODEL, DMODEL);
  attn_kernel<<<dim3(32, 32), 256, 0, stream>>>(qws, kws, vws, out_w, hbf);
  gemm128<1><<<dim3(32, 8), 256, 0, stream>>>(hbf, w2T, b_proj, out_attn, nullptr, nullptr,
                                              nullptr, MTOT, DMODEL, DMODEL);
}